// Round 1
// baseline (344.752 us; speedup 1.0000x reference)
//
#include <hip/hip_runtime.h>
#include <hip/hip_bf16.h>

// KL-style loss: mean_n [ -sum_y target[n,y] * log_softmax(pred)[n,y] ]
// N = 4194304 rows, C = 10, fp32 in, scalar fp32 out.
// Memory-bound streaming reduction: target = HBM BW (~53 us floor at 6.3 TB/s).

#define N_ROWS 4194304
#define C_DIM 10
#define ROWS_PER_THREAD 2   // 2 rows * 10 floats = 20 floats = 5 x float4 (16B aligned)
#define BLOCK 256

__global__ __launch_bounds__(BLOCK) void kl_loss_kernel(
    const float* __restrict__ pred,
    const float* __restrict__ tgt,
    float* __restrict__ out)
{
    const int tid = blockIdx.x * BLOCK + threadIdx.x;

    // Each thread loads 2 contiguous rows (80 B) of pred and tgt as 5 float4 each.
    const float4* p4 = reinterpret_cast<const float4*>(pred) + (size_t)tid * 5;
    const float4* t4 = reinterpret_cast<const float4*>(tgt)  + (size_t)tid * 5;

    float p[20], t[20];
#pragma unroll
    for (int i = 0; i < 5; ++i) {
        float4 a = p4[i];
        p[4 * i + 0] = a.x; p[4 * i + 1] = a.y; p[4 * i + 2] = a.z; p[4 * i + 3] = a.w;
    }
#pragma unroll
    for (int i = 0; i < 5; ++i) {
        float4 a = t4[i];
        t[4 * i + 0] = a.x; t[4 * i + 1] = a.y; t[4 * i + 2] = a.z; t[4 * i + 3] = a.w;
    }

    float local = 0.0f;
#pragma unroll
    for (int r = 0; r < ROWS_PER_THREAD; ++r) {
        const float* x  = p + r * C_DIM;
        const float* ty = t + r * C_DIM;

        float m = x[0];
#pragma unroll
        for (int i = 1; i < C_DIM; ++i) m = fmaxf(m, x[i]);

        float s = 0.0f, dot = 0.0f, st = 0.0f;
#pragma unroll
        for (int i = 0; i < C_DIM; ++i) {
            s   += __expf(x[i] - m);
            dot  = fmaf(ty[i], x[i], dot);
            st  += ty[i];
        }
        float lse = m + __logf(s);
        // -sum_y t_y * (x_y - lse) = st*lse - dot
        local += st * lse - dot;
    }

    // Wave-64 shuffle reduction
#pragma unroll
    for (int off = 32; off > 0; off >>= 1)
        local += __shfl_down(local, off, 64);

    // Block reduction across 4 waves via LDS
    __shared__ float sdata[BLOCK / 64];
    const int lane = threadIdx.x & 63;
    const int wid  = threadIdx.x >> 6;
    if (lane == 0) sdata[wid] = local;
    __syncthreads();

    if (threadIdx.x == 0) {
        float b = sdata[0] + sdata[1] + sdata[2] + sdata[3];
        atomicAdd(out, b * (1.0f / (float)N_ROWS));
    }
}

extern "C" void kernel_launch(void* const* d_in, const int* in_sizes, int n_in,
                              void* d_out, int out_size, void* d_ws, size_t ws_size,
                              hipStream_t stream)
{
    const float* pred = (const float*)d_in[0];
    const float* tgt  = (const float*)d_in[1];
    float* out = (float*)d_out;

    // d_out is poisoned (0xAA) before every call; zero it for the atomic accumulate.
    hipMemsetAsync(out, 0, sizeof(float), stream);

    const int threads = N_ROWS / ROWS_PER_THREAD;           // 2,097,152
    const int blocks  = threads / BLOCK;                    // 8,192
    kl_loss_kernel<<<blocks, BLOCK, 0, stream>>>(pred, tgt, out);
}